// Round 2
// baseline (32428.033 us; speedup 1.0000x reference)
//
#include <hip/hip_runtime.h>
#include <hip/hip_bf16.h>

// DecoderRNN: 3-layer GRU, B=512, S=200, H=1024, V=100, teacher-forced scan.
// v2: layer-pipelined DIAGONAL kernels. Diagonal d runs concurrently:
//   G0(t=d), G1(t=d-1), G2(t=d-2), OUT(t=d-3)  -> 203 launches total.
// Gate blocks: Mt=128 x Ng=64(per gate, x3 gates), 4 waves, 32x32x16 bf16
// MFMA, K-slab=32 double-buffered in LDS (40 KB) with early prefetch.
// No cross-wave K-reduction: i_n / h_n separated by accumulator switch at
// the wih|whh K midpoint (slab 32 of 64). GRU cell fused in epilogue.

typedef __hip_bfloat16 bf16;
typedef __attribute__((ext_vector_type(8))) short short8;
typedef __attribute__((ext_vector_type(8))) unsigned short ushort8;
typedef __attribute__((ext_vector_type(16))) float f32x16;

#define B_ 512
#define S_ 200
#define H_ 1024
#define V_ 100

__device__ __forceinline__ float bf2f(bf16 x) { return __bfloat162float(x); }
__device__ __forceinline__ float us2f(unsigned short u) {
  return __uint_as_float(((unsigned)u) << 16);
}

// LDS per buffer: A 512 granules (8192 B) + B 768 granules (12288 B) = 20480 B
// Two buffers = 40960 B. Granule (row,kc) stored at slot row*4 + (kc^((row>>1)&3)):
// staging stays 64B-coalesced, frag reads put 8 consecutive lanes on 8
// distinct 16B bank-quads (conflict-free ds_read_b128).
__device__ __forceinline__ void stage_slab(
    char* smem, int buf, int it, int tid, int w, int mb, int nb, int KTOT,
    const bf16* __restrict__ A0, const bf16* __restrict__ A1,
    const bf16* __restrict__ Wp) {
  const int kbase = it * 32;
  char* base = smem + buf * 20480;
#pragma unroll
  for (int c = 0; c < 5; ++c) {
    const int G = c * 256 + tid;
    const char* gp;
    if (G < 512) {  // A granule: row in [0,128), kcs in [0,4)
      int row = G >> 2, kcs = G & 3;
      int kc = kcs ^ ((row >> 1) & 3);
      int k = kbase + kc * 8;
      const bf16* src = A0;
      if (k >= 1024) { src = A1; k -= 1024; }  // uniform per-slab
      gp = (const char*)(src + (mb * 128 + row) * H_ + k);
    } else {        // B granule: brow = g*64+nl in [0,192)
      int Gb = G - 512;
      int brow = Gb >> 2, kcs = Gb & 3;
      int kc = kcs ^ ((brow >> 1) & 3);
      int g = brow >> 6, nl = brow & 63;
      gp = (const char*)(Wp + (size_t)(g * 1024 + nb * 64 + nl) * KTOT +
                         kbase + kc * 8);
    }
    char* lp = base + (c * 256 + w * 64) * 16;  // wave-uniform base + lane*16
    __builtin_amdgcn_global_load_lds(
        (const __attribute__((address_space(1))) void*)gp,
        (__attribute__((address_space(3))) void*)lp, 16, 0, 0);
  }
}

template <bool PH>  // PH: accumulate gate-n into aNi (wih phase) else aNh
__device__ __forceinline__ void compute_slab(
    const char* base, int lane, int wm, int wn,
    f32x16 aR[2], f32x16 aZ[2], f32x16 aNi[2], f32x16 aNh[2]) {
#pragma unroll
  for (int kk = 0; kk < 2; ++kk) {
    const int kc = kk * 2 + (lane >> 5);
    const int r0 = wm * 64 + (lane & 31);
    const int r1 = r0 + 32;
    short8 a0 = *(const short8*)(base + (r0 * 4 + (kc ^ ((r0 >> 1) & 3))) * 16);
    short8 a1 = *(const short8*)(base + (r1 * 4 + (kc ^ ((r1 >> 1) & 3))) * 16);
    const int nl = wn * 32 + (lane & 31);
    const int sw = kc ^ ((nl >> 1) & 3);
    short8 b0 = *(const short8*)(base + 8192 + ((0 * 64 + nl) * 4 + sw) * 16);
    short8 b1 = *(const short8*)(base + 8192 + ((1 * 64 + nl) * 4 + sw) * 16);
    short8 b2 = *(const short8*)(base + 8192 + ((2 * 64 + nl) * 4 + sw) * 16);
    aR[0] = __builtin_amdgcn_mfma_f32_32x32x16_bf16(a0, b0, aR[0], 0, 0, 0);
    aR[1] = __builtin_amdgcn_mfma_f32_32x32x16_bf16(a1, b0, aR[1], 0, 0, 0);
    aZ[0] = __builtin_amdgcn_mfma_f32_32x32x16_bf16(a0, b1, aZ[0], 0, 0, 0);
    aZ[1] = __builtin_amdgcn_mfma_f32_32x32x16_bf16(a1, b1, aZ[1], 0, 0, 0);
    if (PH) {
      aNi[0] = __builtin_amdgcn_mfma_f32_32x32x16_bf16(a0, b2, aNi[0], 0, 0, 0);
      aNi[1] = __builtin_amdgcn_mfma_f32_32x32x16_bf16(a1, b2, aNi[1], 0, 0, 0);
    } else {
      aNh[0] = __builtin_amdgcn_mfma_f32_32x32x16_bf16(a0, b2, aNh[0], 0, 0, 0);
      aNh[1] = __builtin_amdgcn_mfma_f32_32x32x16_bf16(a1, b2, aNh[1], 0, 0, 0);
    }
  }
}

__device__ void gates_role(char* smem, int gi, bool l0, int KTOT, int t,
    const bf16* __restrict__ A0, const bf16* __restrict__ A1,
    const bf16* __restrict__ Wp, const float* __restrict__ b4,
    const float* __restrict__ table, const float* __restrict__ gprec,
    const int* __restrict__ inputs, const bf16* __restrict__ hprev,
    bf16* __restrict__ hout) {
  const int tid = threadIdx.x, lane = tid & 63, w = tid >> 6;
  const int wm = w & 1, wn = w >> 1;
  const int mb = gi & 3, nb = gi >> 2;
  const int NITER = KTOT >> 5;

  f32x16 aR[2], aZ[2], aNi[2], aNh[2];
#pragma unroll
  for (int s = 0; s < 2; ++s)
#pragma unroll
    for (int j = 0; j < 16; ++j) {
      aR[s][j] = 0.f; aZ[s][j] = 0.f; aNi[s][j] = 0.f; aNh[s][j] = 0.f;
    }

  stage_slab(smem, 0, 0, tid, w, mb, nb, KTOT, A0, A1, Wp);
  __syncthreads();
  for (int it = 0; it < NITER; ++it) {
    const int buf = it & 1;
    if (it + 1 < NITER)  // prefetch next slab into the other buffer (async)
      stage_slab(smem, buf ^ 1, it + 1, tid, w, mb, nb, KTOT, A0, A1, Wp);
    const char* base = smem + buf * 20480;
    if (!l0 && it < 32)
      compute_slab<true>(base, lane, wm, wn, aR, aZ, aNi, aNh);
    else
      compute_slab<false>(base, lane, wm, wn, aR, aZ, aNi, aNh);
    __syncthreads();  // drains prefetch (vmcnt0) + guards buffer reuse
  }

  // ---- fused GRU epilogue: waves own disjoint outputs ----
  const int nl = lane & 31;
  const int n = nb * 64 + wn * 32 + nl;
  const float br = b4[n], bz = b4[1024 + n];
  const float bin = b4[2048 + n], bhn = b4[3072 + n];
#pragma unroll
  for (int s = 0; s < 2; ++s) {
#pragma unroll
    for (int j = 0; j < 16; ++j) {
      // C/D (32x32): col = lane&31, row = 4*(lane>>5)+(j&3)+8*(j>>2)
      const int mloc = 4 * (lane >> 5) + (j & 3) + 8 * (j >> 2);
      const int b = mb * 128 + wm * 64 + s * 32 + mloc;
      float rt = aR[s][j] + br;
      float zt = aZ[s][j] + bz;
      float hn, npre;
      if (l0) {
        int tok = (t == 0) ? 1 : inputs[b * S_ + (t - 1)];
        const float* tb = table + tok * 3072;
        const float* gp = gprec + b * 3072;
        rt += tb[n] + gp[n];
        zt += tb[1024 + n] + gp[1024 + n];
        hn = aNh[s][j] + bhn;                 // all K is whh
        npre = tb[2048 + n] + gp[2048 + n];   // i_n precomputed (incl bih0)
      } else {
        hn = aNh[s][j] + bhn;                 // slabs 32..63 = whh
        npre = aNi[s][j] + bin;               // slabs 0..31  = wih
      }
      float r = 1.f / (1.f + __expf(-rt));
      float z = 1.f / (1.f + __expf(-zt));
      float nn = npre + r * hn;
      float e2 = __expf(2.f * nn);
      float th = 1.f - 2.f / (e2 + 1.f);      // tanh, inf-safe
      float hp = bf2f(hprev[b * H_ + n]);
      hout[b * H_ + n] = __float2bfloat16((1.f - z) * th + z * hp);
    }
  }
}

__device__ void out_role(char* smem, int ob, int t, const bf16* __restrict__ h2,
    const bf16* __restrict__ owTv, const float* __restrict__ logitde,
    float* __restrict__ out) {
  float* hs = (float*)smem;  // [2][1024] = 8 KB
  const int tid = threadIdx.x;
  {
    const int e = tid * 8;
    const int r = e >> 10, k = e & 1023;
    const int b = ob * 2 + r;
    ushort8 hv = *(const ushort8*)(h2 + b * H_ + k);
#pragma unroll
    for (int i = 0; i < 8; ++i) hs[r * 1024 + k + i] = us2f(hv[i]);
  }
  __syncthreads();
  const int r = tid >> 7, v = tid & 127;
  if (v < V_) {
    const int b = ob * 2 + r;
    float acc = logitde[b * V_ + v];
    const ushort8* row = (const ushort8*)(owTv + v * H_);
    const float* h = hs + r * 1024;
#pragma unroll 4
    for (int k8 = 0; k8 < H_ / 8; ++k8) {
      ushort8 wv = row[k8];
#pragma unroll
      for (int i = 0; i < 8; ++i) acc += h[k8 * 8 + i] * us2f(wv[i]);
    }
    out[(b * S_ + t) * V_ + v] = acc;
  }
}

// ---------------------------------------------------------------------------
// Diagonal kernel: 448 blocks. [0,64)=G0, [64,128)=G1, [128,192)=G2,
// [192,448)=OUT (2 batch rows each).
// ---------------------------------------------------------------------------
__global__ __launch_bounds__(256, 2) void diag_kernel(
    int d, const int* __restrict__ inputs,
    const bf16* __restrict__ Wp0, const bf16* __restrict__ Wp1,
    const bf16* __restrict__ Wp2, const float* __restrict__ bias4,
    const float* __restrict__ table, const float* __restrict__ gprec0,
    const bf16* __restrict__ owTv, const float* __restrict__ logitde,
    bf16* __restrict__ hbuf, float* __restrict__ out) {
  __shared__ char smem[40960];
  const int bi = blockIdx.x;
  const int par = d & 1;
#define HBp(p, l) (hbuf + ((p) * 3 + (l)) * (B_ * H_))
  if (bi < 192) {
    const int layer = bi >> 6, gi = bi & 63;
    const int t = d - layer;
    if (t < 0 || t >= S_) return;
    const bf16 *A0, *A1, *hprev; bf16* ho;
    const bf16* Wp; const float* b4; int KTOT;
    if (layer == 0) {
      A0 = HBp(1 - par, 0); A1 = A0; hprev = A0; ho = HBp(par, 0);
      Wp = Wp0; b4 = bias4; KTOT = 1024;
    } else if (layer == 1) {
      A0 = HBp(1 - par, 0); A1 = HBp(par, 1); hprev = A1; ho = HBp(1 - par, 1);
      Wp = Wp1; b4 = bias4 + 4096; KTOT = 2048;
    } else {
      A0 = HBp(par, 1); A1 = HBp(1 - par, 2); hprev = A1; ho = HBp(par, 2);
      Wp = Wp2; b4 = bias4 + 8192; KTOT = 2048;
    }
    gates_role(smem, gi, layer == 0, KTOT, t, A0, A1, Wp, b4, table, gprec0,
               inputs, hprev, ho);
  } else {
    const int t = d - 3;
    if (t < 0 || t >= S_) return;
    out_role(smem, bi - 192, t, HBp(1 - par, 2), owTv, logitde, out);
  }
#undef HBp
}

// ---------------------------------------------------------------------------
// fp32 precompute GEMM: C[m][n] = sum_k A[m*lda+k]*W[n*ldw+woff+k] + bias[n]
// ---------------------------------------------------------------------------
__global__ __launch_bounds__(256) void pgemm(
    const float* __restrict__ A, int lda, const float* __restrict__ W, int ldw,
    int woff, const float* __restrict__ bias, float* __restrict__ C,
    int M, int N, int K) {
  __shared__ float As[64][33];
  __shared__ float Ws[64][33];
  const int tid = threadIdx.x;
  const int tx = tid & 15, ty = tid >> 4;
  const int mb = blockIdx.x * 64, nb = blockIdx.y * 64;
  float acc[4][4];
#pragma unroll
  for (int i = 0; i < 4; ++i)
#pragma unroll
    for (int j = 0; j < 4; ++j) acc[i][j] = 0.f;

  for (int k0 = 0; k0 < K; k0 += 32) {
#pragma unroll
    for (int s = 0; s < 8; ++s) {
      int idx = s * 256 + tid;
      int r = idx >> 5, c = idx & 31;
      int m = mb + r;
      As[r][c] = (m < M) ? A[m * lda + k0 + c] : 0.f;
      int n = nb + r;
      Ws[r][c] = (n < N) ? W[n * ldw + woff + k0 + c] : 0.f;
    }
    __syncthreads();
#pragma unroll 8
    for (int kk = 0; kk < 32; ++kk) {
      float a[4], ww[4];
#pragma unroll
      for (int i = 0; i < 4; ++i) a[i] = As[ty * 4 + i][kk];
#pragma unroll
      for (int j = 0; j < 4; ++j) ww[j] = Ws[tx * 4 + j][kk];
#pragma unroll
      for (int i = 0; i < 4; ++i)
#pragma unroll
        for (int j = 0; j < 4; ++j) acc[i][j] += a[i] * ww[j];
    }
    __syncthreads();
  }
#pragma unroll
  for (int i = 0; i < 4; ++i) {
    int m = mb + ty * 4 + i;
    if (m >= M) continue;
#pragma unroll
    for (int j = 0; j < 4; ++j) {
      int n = nb + tx * 4 + j;
      if (n < N) C[m * N + n] = acc[i][j] + (bias ? bias[n] : 0.f);
    }
  }
}

// --------------------------- small pack kernels ----------------------------
__global__ void k_de(const float* __restrict__ z, const float* __restrict__ c,
                     float* __restrict__ de) {
  int i = blockIdx.x * 256 + threadIdx.x;  // 512*1024
  int b = i >> 10, q = i & 1023;
  de[i] = (q < 512) ? z[b * 512 + q] : c[b * 512 + (q - 512)];
}

__global__ void k_wpack(const float* __restrict__ wih,
                        const float* __restrict__ whh, bf16* __restrict__ Wp,
                        int ktshift) {
  int KT = 1 << ktshift;
  int i = blockIdx.x * 256 + threadIdx.x;
  if (i >= 3072 * KT) return;
  int k = i & (KT - 1);
  int row = i >> ktshift;  // g*1024 + n
  float v = (k < 1024) ? wih[row * 1024 + k] : whh[row * 1024 + (k - 1024)];
  Wp[i] = __float2bfloat16(v);
}

__global__ void k_bias4(const float* __restrict__ bih,
                        const float* __restrict__ bhh, float* __restrict__ dst,
                        int l0) {
  int n = blockIdx.x * 256 + threadIdx.x;
  if (n >= 1024) return;
  dst[n] = l0 ? bhh[n] : bih[n] + bhh[n];
  dst[1024 + n] = l0 ? bhh[1024 + n] : bih[1024 + n] + bhh[1024 + n];
  dst[2048 + n] = l0 ? 0.f : bih[2048 + n];
  dst[3072 + n] = bhh[2048 + n];
}

__global__ void k_owt(const float* __restrict__ out_w, bf16* __restrict__ owTv) {
  int i = blockIdx.x * 256 + threadIdx.x;  // 100*1024
  if (i >= V_ * H_) return;
  int v = i >> 10, k = i & 1023;
  owTv[i] = __float2bfloat16(out_w[v * 2048 + k]);
}

__global__ void k_hinit(const float* __restrict__ hinit, bf16* __restrict__ h0,
                        bf16* __restrict__ h1, bf16* __restrict__ h2) {
  int i = blockIdx.x * 256 + threadIdx.x;  // 512*1024
  bf16 v = __float2bfloat16(hinit[i]);
  h0[i] = v; h1[i] = v; h2[i] = v;
}

// ---------------------------------------------------------------------------
extern "C" void kernel_launch(void* const* d_in, const int* in_sizes, int n_in,
                              void* d_out, int out_size, void* d_ws,
                              size_t ws_size, hipStream_t stream) {
  const int* inputs = (const int*)d_in[0];
  const float* z = (const float*)d_in[1];
  const float* cond = (const float*)d_in[2];
  // d_in[3] = temperature (>=1 -> always teacher-forced)
  const float* emb = (const float*)d_in[4];
  const float* i2h_w = (const float*)d_in[5];
  const float* i2h_b = (const float*)d_in[6];
  const float* out_w = (const float*)d_in[7];
  const float* out_b = (const float*)d_in[8];
  const float* wih0 = (const float*)d_in[9];
  const float* whh0 = (const float*)d_in[10];
  const float* bih0 = (const float*)d_in[11];
  const float* bhh0 = (const float*)d_in[12];
  const float* wih1 = (const float*)d_in[13];
  const float* whh1 = (const float*)d_in[14];
  const float* bih1 = (const float*)d_in[15];
  const float* bhh1 = (const float*)d_in[16];
  const float* wih2 = (const float*)d_in[17];
  const float* whh2 = (const float*)d_in[18];
  const float* bih2 = (const float*)d_in[19];
  const float* bhh2 = (const float*)d_in[20];
  float* out = (float*)d_out;

  char* p = (char*)d_ws;
  float* de = (float*)(p + 0);                 //  2 MB
  float* gprec0 = (float*)(p + 2097152);       //  6.29 MB
  float* table = (float*)(p + 8388608);        //  1.23 MB
  float* hinit = (float*)(p + 9617408);        //  2 MB
  float* logitde = (float*)(p + 11714560);     //  0.2 MB
  float* bias4 = (float*)(p + 11919360);       //  48 KB [3][4][1024]
  bf16* Wp0 = (bf16*)(p + 11968512);           //  6.29 MB
  bf16* Wp1 = (bf16*)(p + 18259968);           // 12.58 MB
  bf16* Wp2 = (bf16*)(p + 30842880);           // 12.58 MB
  bf16* owTv = (bf16*)(p + 43425792);          //  0.2 MB
  bf16* hbuf = (bf16*)(p + 43630592);          //  6.29 MB [2][3][512][1024]
#define HB(par, l) (hbuf + ((par) * 3 + (l)) * (B_ * H_))

  // ---- one-time precompute ----
  k_de<<<2048, 256, 0, stream>>>(z, cond, de);
  pgemm<<<dim3(8, 48), 256, 0, stream>>>(de, 1024, wih0, 1536, 512, bih0,
                                         gprec0, 512, 3072, 1024);
  pgemm<<<dim3(2, 48), 256, 0, stream>>>(emb, 512, wih0, 1536, 0, nullptr,
                                         table, 100, 3072, 512);
  pgemm<<<dim3(8, 16), 256, 0, stream>>>(de, 1024, i2h_w, 1024, 0, i2h_b,
                                         hinit, 512, 1024, 1024);
  pgemm<<<dim3(8, 2), 256, 0, stream>>>(de, 1024, out_w, 2048, 1024, out_b,
                                        logitde, 512, 100, 1024);
  k_bias4<<<4, 256, 0, stream>>>(bhh0, bhh0, bias4, 1);
  k_bias4<<<4, 256, 0, stream>>>(bih1, bhh1, bias4 + 4096, 0);
  k_bias4<<<4, 256, 0, stream>>>(bih2, bhh2, bias4 + 8192, 0);
  k_wpack<<<(3072 * 1024 + 255) / 256, 256, 0, stream>>>(whh0, whh0, Wp0, 10);
  k_wpack<<<(3072 * 2048 + 255) / 256, 256, 0, stream>>>(wih1, whh1, Wp1, 11);
  k_wpack<<<(3072 * 2048 + 255) / 256, 256, 0, stream>>>(wih2, whh2, Wp2, 11);
  k_owt<<<400, 256, 0, stream>>>(out_w, owTv);
  // h(-1) buffers live at parity 1 (first consumers read 1-par with d=0)
  k_hinit<<<2048, 256, 0, stream>>>(hinit, HB(1, 0), HB(1, 1), HB(1, 2));

  // ---- diagonal-pipelined scan: d = 0 .. 202 ----
  for (int d = 0; d < S_ + 3; ++d) {
    diag_kernel<<<448, 256, 0, stream>>>(d, inputs, Wp0, Wp1, Wp2, bias4,
                                         table, gprec0, owTv, logitde, hbuf,
                                         out);
  }
#undef HB
}